// Round 21
// baseline (941.083 us; speedup 1.0000x reference)
//
#include <hip/hip_runtime.h>
#include <hip/hip_bf16.h>

#define B_ 32
#define T_ 2000
#define S_ 400
#define C0_ 80
#define H_ 256

static constexpr float NEGV = -1e9f;
static constexpr int NMU  = B_ * T_ * S_;       // 25,600,000
static constexpr int NPI  = 2 * NMU;            // 51,200,000

typedef _Float16 f16x8 __attribute__((ext_vector_type(8)));
typedef _Float16 f16x4v __attribute__((ext_vector_type(4)));
typedef _Float16 f16x2v __attribute__((ext_vector_type(2)));
typedef float    f32x4 __attribute__((ext_vector_type(4)));

// ---------------- weight repack: wcat[co][k*CPAD+ci] = w[k][ci][co] ------
__global__ __launch_bounds__(256)
void wprep(const float* __restrict__ w, _Float16* __restrict__ wcat,
           int CIN, int CPAD)
{
  const int tot = 256 * 5 * CPAD;
  int idx = blockIdx.x * 256 + threadIdx.x;
  if (idx >= tot) return;
  int co  = idx / (5 * CPAD);
  int rem = idx - co * (5 * CPAD);
  int k   = rem / CPAD;
  int ci  = rem - k * CPAD;
  float v = (ci < CIN) ? w[((size_t)k * CIN + ci) * H_ + co] : 0.f;
  wcat[idx] = (_Float16)v;
}

// ---------------- cast src_enc to f16 ------------------------------------
__global__ __launch_bounds__(256)
void ecast(const float* __restrict__ e, _Float16* __restrict__ ef)
{
  const int n4 = B_ * S_ * H_ / 4;
  int idx = blockIdx.x * 256 + threadIdx.x;
  if (idx >= n4) return;
  float4 v = ((const float4*)e)[idx];
  _Float16* d = ef + (size_t)idx * 4;
  d[0] = (_Float16)v.x; d[1] = (_Float16)v.y;
  d[2] = (_Float16)v.z; d[3] = (_Float16)v.w;
}

// ---------------- conv1d (K=5, SAME) + bias + tanh via f16 MFMA ----------
template<int CIN, int CPAD, bool INF32, bool OUTF32>
__global__ __launch_bounds__(256)
void conv_mfma(const void* __restrict__ xin, const _Float16* __restrict__ wcat,
               const float* __restrict__ bias, void* __restrict__ yout)
{
  constexpr int KK  = 5 * CPAD;      // 480 / 1280
  constexpr int NS  = KK / 32;       // 15 / 40
  constexpr int STR = CPAD + 8;      // LDS row stride
  __shared__ _Float16 xs[68 * STR];
  const int b   = blockIdx.y;
  const int t0  = blockIdx.x * 64;
  const int tid = threadIdx.x;
  const int w   = tid >> 6;
  const int l   = tid & 63;

  if constexpr (INF32) {
    const float* xb = (const float*)xin + (size_t)b * T_ * CIN;
    constexpr int NG = CPAD / 4;
    for (int idx = tid; idx < 68 * NG; idx += 256) {
      int j = idx / NG, g = idx - j * NG;
      int t = t0 - 2 + j;
      int c = g * 4;
      float4 v = make_float4(0.f, 0.f, 0.f, 0.f);
      if (t >= 0 && t < T_ && c < CIN) v = *(const float4*)&xb[(size_t)t * CIN + c];
      _Float16* d = &xs[j * STR + c];
      d[0] = (_Float16)v.x; d[1] = (_Float16)v.y;
      d[2] = (_Float16)v.z; d[3] = (_Float16)v.w;
    }
  } else {
    const _Float16* xb = (const _Float16*)xin + (size_t)b * T_ * CIN;
    constexpr int NG = CPAD / 8;
    for (int idx = tid; idx < 68 * NG; idx += 256) {
      int j = idx / NG, g = idx - j * NG;
      int t = t0 - 2 + j;
      f16x8 v = {(_Float16)0,(_Float16)0,(_Float16)0,(_Float16)0,
                 (_Float16)0,(_Float16)0,(_Float16)0,(_Float16)0};
      if (t >= 0 && t < T_) v = *(const f16x8*)&xb[(size_t)t * CIN + g * 8];
      *(f16x8*)&xs[j * STR + g * 8] = v;
    }
  }
  __syncthreads();

  const int lr = l & 15;
  const int lk = (l >> 4) * 8;

  f32x4 acc[4][4];
  const f32x4 zz = {0.f, 0.f, 0.f, 0.f};
#pragma unroll
  for (int i = 0; i < 4; i++)
#pragma unroll
    for (int j = 0; j < 4; j++) acc[i][j] = zz;

  const _Float16* wbase = wcat + (size_t)(w * 64 + lr) * KK + lk;

  for (int kk = 0; kk < NS; kk++) {
    const int p  = kk * 32;
    const int k  = p / CPAD;
    const int ci = p - k * CPAD;
    f16x8 a0 = *(const f16x8*)&xs[( 0 + lr + k) * STR + ci + lk];
    f16x8 a1 = *(const f16x8*)&xs[(16 + lr + k) * STR + ci + lk];
    f16x8 a2 = *(const f16x8*)&xs[(32 + lr + k) * STR + ci + lk];
    f16x8 a3 = *(const f16x8*)&xs[(48 + lr + k) * STR + ci + lk];
    f16x8 w0 = *(const f16x8*)&wbase[(size_t)( 0) * KK + p];
    f16x8 w1 = *(const f16x8*)&wbase[(size_t)(16) * KK + p];
    f16x8 w2 = *(const f16x8*)&wbase[(size_t)(32) * KK + p];
    f16x8 w3 = *(const f16x8*)&wbase[(size_t)(48) * KK + p];
    acc[0][0] = __builtin_amdgcn_mfma_f32_16x16x32_f16(a0, w0, acc[0][0], 0, 0, 0);
    acc[0][1] = __builtin_amdgcn_mfma_f32_16x16x32_f16(a0, w1, acc[0][1], 0, 0, 0);
    acc[0][2] = __builtin_amdgcn_mfma_f32_16x16x32_f16(a0, w2, acc[0][2], 0, 0, 0);
    acc[0][3] = __builtin_amdgcn_mfma_f32_16x16x32_f16(a0, w3, acc[0][3], 0, 0, 0);
    acc[1][0] = __builtin_amdgcn_mfma_f32_16x16x32_f16(a1, w0, acc[1][0], 0, 0, 0);
    acc[1][1] = __builtin_amdgcn_mfma_f32_16x16x32_f16(a1, w1, acc[1][1], 0, 0, 0);
    acc[1][2] = __builtin_amdgcn_mfma_f32_16x16x32_f16(a1, w2, acc[1][2], 0, 0, 0);
    acc[1][3] = __builtin_amdgcn_mfma_f32_16x16x32_f16(a1, w3, acc[1][3], 0, 0, 0);
    acc[2][0] = __builtin_amdgcn_mfma_f32_16x16x32_f16(a2, w0, acc[2][0], 0, 0, 0);
    acc[2][1] = __builtin_amdgcn_mfma_f32_16x16x32_f16(a2, w1, acc[2][1], 0, 0, 0);
    acc[2][2] = __builtin_amdgcn_mfma_f32_16x16x32_f16(a2, w2, acc[2][2], 0, 0, 0);
    acc[2][3] = __builtin_amdgcn_mfma_f32_16x16x32_f16(a2, w3, acc[2][3], 0, 0, 0);
    acc[3][0] = __builtin_amdgcn_mfma_f32_16x16x32_f16(a3, w0, acc[3][0], 0, 0, 0);
    acc[3][1] = __builtin_amdgcn_mfma_f32_16x16x32_f16(a3, w1, acc[3][1], 0, 0, 0);
    acc[3][2] = __builtin_amdgcn_mfma_f32_16x16x32_f16(a3, w2, acc[3][2], 0, 0, 0);
    acc[3][3] = __builtin_amdgcn_mfma_f32_16x16x32_f16(a3, w3, acc[3][3], 0, 0, 0);
  }

#pragma unroll
  for (int ct = 0; ct < 4; ct++) {
    const int co = w * 64 + ct * 16 + lr;
    const float bv = bias[co];
#pragma unroll
    for (int tt = 0; tt < 4; tt++) {
#pragma unroll
      for (int r = 0; r < 4; r++) {
        const int t = t0 + tt * 16 + (l >> 4) * 4 + r;
        if (t < T_) {
          float v = tanhf(acc[tt][ct][r] + bv);
          if constexpr (OUTF32)
            ((float*)yout)[((size_t)b * T_ + t) * H_ + co] = v;
          else
            ((_Float16*)yout)[((size_t)b * T_ + t) * H_ + co] = (_Float16)v;
        }
      }
    }
  }
}

// ---------------- einsum via f16 MFMA + fused column-stats partials ------
__global__ __launch_bounds__(256)
void einsum_mfma(const float* __restrict__ A, const _Float16* __restrict__ E,
                 float* __restrict__ Wg,
                 float* __restrict__ pm, float* __restrict__ pl)
{
  constexpr int STR = H_ + 8;        // 264
  __shared__ _Float16 xs[64 * STR];  // 33.8 KB
  const int b   = blockIdx.z;
  const int t0  = blockIdx.x * 64;
  const int s0  = blockIdx.y * 256;
  const int tid = threadIdx.x;
  const int w   = tid >> 6;
  const int l   = tid & 63;

  const float* Ab = A + (size_t)b * T_ * H_;
  for (int idx = tid; idx < 64 * 64; idx += 256) {
    int row = idx >> 6, g = idx & 63;
    int t = t0 + row;
    float4 v = make_float4(0.f, 0.f, 0.f, 0.f);
    if (t < T_) v = *(const float4*)&Ab[(size_t)t * H_ + 4 * g];
    _Float16* d = &xs[row * STR + 4 * g];
    d[0] = (_Float16)v.x; d[1] = (_Float16)v.y;
    d[2] = (_Float16)v.z; d[3] = (_Float16)v.w;
  }
  __syncthreads();

  const int lr = l & 15;
  const int lk = (l >> 4) * 8;

  f32x4 acc[4][4];
  const f32x4 zz = {0.f, 0.f, 0.f, 0.f};
#pragma unroll
  for (int i = 0; i < 4; i++)
#pragma unroll
    for (int j = 0; j < 4; j++) acc[i][j] = zz;

  const _Float16* Eb = E + (size_t)b * S_ * H_;
  const int sr = s0 + w * 64 + lr;
  const _Float16* e0 = Eb + (size_t)((sr      < S_) ? sr      : (S_ - 1)) * H_ + lk;
  const _Float16* e1 = Eb + (size_t)((sr + 16 < S_) ? sr + 16 : (S_ - 1)) * H_ + lk;
  const _Float16* e2 = Eb + (size_t)((sr + 32 < S_) ? sr + 32 : (S_ - 1)) * H_ + lk;
  const _Float16* e3 = Eb + (size_t)((sr + 48 < S_) ? sr + 48 : (S_ - 1)) * H_ + lk;

#pragma unroll
  for (int kk = 0; kk < 8; kk++) {
    const int p = kk * 32;
    f16x8 a0 = *(const f16x8*)&xs[( 0 + lr) * STR + p + lk];
    f16x8 a1 = *(const f16x8*)&xs[(16 + lr) * STR + p + lk];
    f16x8 a2 = *(const f16x8*)&xs[(32 + lr) * STR + p + lk];
    f16x8 a3 = *(const f16x8*)&xs[(48 + lr) * STR + p + lk];
    f16x8 w0 = *(const f16x8*)&e0[p];
    f16x8 w1 = *(const f16x8*)&e1[p];
    f16x8 w2 = *(const f16x8*)&e2[p];
    f16x8 w3 = *(const f16x8*)&e3[p];
    acc[0][0] = __builtin_amdgcn_mfma_f32_16x16x32_f16(a0, w0, acc[0][0], 0, 0, 0);
    acc[0][1] = __builtin_amdgcn_mfma_f32_16x16x32_f16(a0, w1, acc[0][1], 0, 0, 0);
    acc[0][2] = __builtin_amdgcn_mfma_f32_16x16x32_f16(a0, w2, acc[0][2], 0, 0, 0);
    acc[0][3] = __builtin_amdgcn_mfma_f32_16x16x32_f16(a0, w3, acc[0][3], 0, 0, 0);
    acc[1][0] = __builtin_amdgcn_mfma_f32_16x16x32_f16(a1, w0, acc[1][0], 0, 0, 0);
    acc[1][1] = __builtin_amdgcn_mfma_f32_16x16x32_f16(a1, w1, acc[1][1], 0, 0, 0);
    acc[1][2] = __builtin_amdgcn_mfma_f32_16x16x32_f16(a1, w2, acc[1][2], 0, 0, 0);
    acc[1][3] = __builtin_amdgcn_mfma_f32_16x16x32_f16(a1, w3, acc[1][3], 0, 0, 0);
    acc[2][0] = __builtin_amdgcn_mfma_f32_16x16x32_f16(a2, w0, acc[2][0], 0, 0, 0);
    acc[2][1] = __builtin_amdgcn_mfma_f32_16x16x32_f16(a2, w1, acc[2][1], 0, 0, 0);
    acc[2][2] = __builtin_amdgcn_mfma_f32_16x16x32_f16(a2, w2, acc[2][2], 0, 0, 0);
    acc[2][3] = __builtin_amdgcn_mfma_f32_16x16x32_f16(a2, w3, acc[2][3], 0, 0, 0);
    acc[3][0] = __builtin_amdgcn_mfma_f32_16x16x32_f16(a3, w0, acc[3][0], 0, 0, 0);
    acc[3][1] = __builtin_amdgcn_mfma_f32_16x16x32_f16(a3, w1, acc[3][1], 0, 0, 0);
    acc[3][2] = __builtin_amdgcn_mfma_f32_16x16x32_f16(a3, w2, acc[3][2], 0, 0, 0);
    acc[3][3] = __builtin_amdgcn_mfma_f32_16x16x32_f16(a3, w3, acc[3][3], 0, 0, 0);
  }

  float* Wb = Wg + (size_t)b * T_ * S_;
#pragma unroll
  for (int ct = 0; ct < 4; ct++) {
    const int s = s0 + w * 64 + ct * 16 + lr;
    if (s < S_) {
#pragma unroll
      for (int tt = 0; tt < 4; tt++) {
#pragma unroll
        for (int r = 0; r < 4; r++) {
          const int t = t0 + tt * 16 + (l >> 4) * 4 + r;
          if (t < T_) Wb[(size_t)t * S_ + s] = acc[tt][ct][r];
        }
      }
    }
  }

  // ---- fused per-(t-block, s) column stats ----
  const int tblk = blockIdx.x;
#pragma unroll
  for (int ct = 0; ct < 4; ct++) {
    float M = -3e38f;
#pragma unroll
    for (int tt = 0; tt < 4; tt++)
#pragma unroll
      for (int r = 0; r < 4; r++) {
        const int t = t0 + tt * 16 + (l >> 4) * 4 + r;
        if (t < T_) M = fmaxf(M, acc[tt][ct][r]);
      }
    float L = 0.f;
#pragma unroll
    for (int tt = 0; tt < 4; tt++)
#pragma unroll
      for (int r = 0; r < 4; r++) {
        const int t = t0 + tt * 16 + (l >> 4) * 4 + r;
        if (t < T_) L += __expf(acc[tt][ct][r] - M);
      }
#pragma unroll
    for (int mk = 16; mk <= 32; mk <<= 1) {
      float Mo = __shfl_xor(M, mk);
      float Lo = __shfl_xor(L, mk);
      float Mn = fmaxf(M, Mo);
      L = L * __expf(M - Mn) + Lo * __expf(Mo - Mn);
      M = Mn;
    }
    if ((l >> 4) == 0) {
      const int s = s0 + w * 64 + ct * 16 + lr;
      if (s < S_) {
        pm[((size_t)b * 32 + tblk) * S_ + s] = M;
        pl[((size_t)b * 32 + tblk) * S_ + s] = L;
      }
    }
  }
}

// ---------------- reduce 32 t-block partials -> mu[b][0][s] = M + lnL ----
__global__ __launch_bounds__(256)
void stats_reduce(const float* __restrict__ pm, const float* __restrict__ pl,
                  float* __restrict__ statsMu)
{
  int idx = blockIdx.x * 256 + threadIdx.x;
  if (idx >= B_ * S_) return;
  int b = idx / S_, s = idx - b * S_;
  float M = -3e38f, L = 0.f;
#pragma unroll 4
  for (int k = 0; k < 32; k++) {
    float m = pm[((size_t)b * 32 + k) * S_ + s];
    float l = pl[((size_t)b * 32 + k) * S_ + s];
    float Mn = fmaxf(M, m);
    L = L * __expf(M - Mn) + l * __expf(m - Mn);
    M = Mn;
  }
  statsMu[(size_t)b * T_ * S_ + s] = M + __logf(L);
}

// ---------------- normalize: al = exp(raw-stat); wdpf16 = al*msk*log2e ---
// Stats read from mu[b][0][:]; wdp written as f16 into the TAIL QUARTER of
// batch b's pi chunk (1.6 MB; overwritten by dp's pi rows 1500+ only AFTER
// the corresponding wdp rows are consumed -- verified phase ordering).
__global__ __launch_bounds__(256)
void norm_kernel(float* __restrict__ al, const float* __restrict__ Mk,
                 const float* __restrict__ statsMu, float* __restrict__ piBase)
{
  constexpr float C2 = 1.44269504f;
  const int gid = blockIdx.x * 256 + threadIdx.x;
  if (gid >= NMU / 4) return;
  const int b   = gid / (T_ * S_ / 4);
  const int rem = gid - b * (T_ * S_ / 4);
  const int t   = rem / (S_ / 4);
  const int s4  = rem % (S_ / 4);
  const float4 st4 = *(const float4*)&statsMu[(size_t)b * T_ * S_ + 4 * s4];
  float4 r = ((const float4*)al)[gid];
  float4 k = ((const float4*)Mk)[gid];
  float4 a;
  a.x = __expf(r.x - st4.x);
  a.y = __expf(r.y - st4.y);
  a.z = __expf(r.z - st4.z);
  a.w = __expf(r.w - st4.w);
  ((float4*)al)[gid] = a;
  _Float16* wdpf = (_Float16*)(piBase + (size_t)b * 1600000 + 1200000);
  f16x4v h = {(_Float16)(a.x * k.x * C2), (_Float16)(a.y * k.y * C2),
              (_Float16)(a.z * k.z * C2), (_Float16)(a.w * k.w * C2)};
  *(f16x4v*)&wdpf[(size_t)t * S_ + 4 * s4] = h;
}

// ---------------- DP: skewed 4-wave pipeline, 24 rows/phase, f16 ring ----
// Wave w owns cols [100w,100w+100) (2 cells/lane); block j = rows
// 24j+1..24j+24 computed at phase p=j+w+1 (base row 0 at p=w). 88 phases.
// Ring: 144 f16 rows (115.2 KB, slot = row mod 144). Prologue stages rows
// 0..24; phase p stages block p+1 (wave w: rows 24(p+1)+1+6w..+5, one DMA
// op per 800B row, lanes<50). Per-wave ops/phase = 6 DMA + 48 stores = 54:
// vmcnt(54) at phase start retires everything >= 2 phases old. bnd[64][4].
// wdp source = f16 tail-quarter of this batch's pi chunk (see norm_kernel);
// pi rows 1500+ overwrite those bytes >= 3 phases after their wdp reads.
__global__ __launch_bounds__(256, 1)
void dp_skew4(float* muOut, float* piBase)
{
  __shared__ _Float16 ring[144 * S_];   // 115.2 KB
  __shared__ float bnd[64][4];
  const int b = blockIdx.x;
  const int w = threadIdx.x >> 6;
  const int l = threadIdx.x & 63;
  const int lc = (l < 50) ? l : 49;
  const bool act = (l < 50);
  const int sc = 100 * w + 2 * lc;

  const _Float16* wbf = (const _Float16*)(piBase + (size_t)b * 1600000 + 1200000);
  float* mub = muOut + (size_t)b * T_ * S_;
  float* pib = piBase + (size_t)(2 * b) * T_ * S_;

  constexpr float LN2  = 0.693147181f;
  constexpr float NEGN = -1.44269504e9f;   // -1e9 * log2(e)

#define DMA(row, slot)                                                      \
  { const char* s_ = (const char*)(wbf + (size_t)(row) * S_);               \
    char* d_ = (char*)ring + ((slot) * 800);                                \
    if (l < 50)                                                             \
      __builtin_amdgcn_global_load_lds(                                     \
        (const __attribute__((address_space(1))) void*)(s_ + l * 16),       \
        (__attribute__((address_space(3))) void*)(d_ + l * 16), 16, 0, 0); }

  // prologue: rows 0..24 (wave w: rows 6w..6w+5; wave 0 also row 24)
#pragma unroll
  for (int i = 0; i < 6; ++i) { const int r0 = 6 * w + i; DMA(r0, r0) }
  if (w == 0) DMA(24, 24)
  asm volatile("s_waitcnt vmcnt(0)" ::: "memory");
  __syncthreads();

  float n0 = NEGN, n1 = NEGN;
  int rs = 1;             // ring slot of row 24j+1 for this wave's next block
  int ds = 25 + 6 * w;    // ring slot of first DMA row at phase 0

  for (int p = 0; p <= 87; ++p) {
    __builtin_amdgcn_s_barrier();
    asm volatile("s_waitcnt vmcnt(54)" ::: "memory");
    const int j = p - w - 1;

    // ---- DMA block p+1: rows 24(p+1)+1+6w .. +5 ----
    {
      const int dr = 24 * (p + 1) + 1 + 6 * w;
#pragma unroll
      for (int q = 0; q < 6; ++q) {
        if (dr + q < T_) {
          int s2 = ds + q; if (s2 >= 144) s2 -= 144;
          DMA(dr + q, s2)
        }
      }
      ds += 24; if (ds >= 144) ds -= 144;
    }

    if (p == w) {
      // base case: row 0 (slot 0, prologue-staged)
      f16x2v c0h = *(const f16x2v*)&ring[sc];
      n0 = (float)c0h[0] + ((sc == 0) ? 0.f : NEGN);
      n1 = (float)c0h[1] + NEGN;
      if (act) {
        *(float2*)&mub[sc] = make_float2(n0 * LN2, n1 * LN2);
        *(float4*)&pib[2 * sc] = make_float4(1.f, 0.f, 1.f, 0.f);
      }
      if (l == 49) bnd[0][w] = n1;
    } else if (j >= 0 && j <= 83) {
      const int tb = 24 * j + 1;
      // ---- hoisted independent reads ----
      float2 cur[24];
      float  bq[24];
#pragma unroll
      for (int k = 0; k < 24; ++k) {
        const int t = tb + k;
        int sk = rs + k; if (sk >= 144) sk -= 144;
        if (t < T_) {
          f16x2v h = *(const f16x2v*)&ring[sk * S_ + sc];
          cur[k] = make_float2((float)h[0], (float)h[1]);
        } else {
          cur[k] = make_float2(0.f, 0.f);
        }
        bq[k] = (w > 0) ? bnd[(t - 1) & 63][w - 1] : NEGN;
      }
      // ---- compute 24 steps ----
      float* mrow = mub + (size_t)tb * S_ + sc;
      float* prow = pib + (size_t)tb * (2 * S_) + 2 * sc;
#pragma unroll
      for (int k = 0; k < 24; ++k) {
        const int t = tb + k;
        if (t < T_) {                                    // wave-uniform
          float sh = __shfl_up(n1, 1);
          float sft0 = (l == 0) ? bq[k] : sh;
          float d0 = n0 - sft0;
          float e0; asm("v_exp_f32 %0, %1" : "=v"(e0) : "v"(-fabsf(d0)));
          float q0 = 1.f + e0;
          float lg0; asm("v_log_f32 %0, %1" : "=v"(lg0) : "v"(q0));
          float rc0; asm("v_rcp_f32 %0, %1" : "=v"(rc0) : "v"(q0));
          float p00 = (d0 >= 0.f) ? rc0 : 1.f - rc0;
          float nn0 = cur[k].x + fmaxf(n0, sft0) + lg0;
          float d1 = n1 - n0;
          float e1; asm("v_exp_f32 %0, %1" : "=v"(e1) : "v"(-fabsf(d1)));
          float q1 = 1.f + e1;
          float lg1; asm("v_log_f32 %0, %1" : "=v"(lg1) : "v"(q1));
          float rc1; asm("v_rcp_f32 %0, %1" : "=v"(rc1) : "v"(q1));
          float p01 = (d1 >= 0.f) ? rc1 : 1.f - rc1;
          float nn1 = cur[k].y + fmaxf(n1, n0) + lg1;
          if (act) {
            *(float2*)mrow = make_float2(nn0 * LN2, nn1 * LN2);
            *(float4*)prow = make_float4(p00, 1.f - p00, p01, 1.f - p01);
          }
          n0 = nn0; n1 = nn1;
          if (l == 49) bnd[t & 63][w] = n1;
        }
        mrow += S_;
        prow += 2 * S_;
      }
      rs += 24; if (rs >= 144) rs -= 144;
    }
    // publish bnd before the next barrier
    asm volatile("s_waitcnt lgkmcnt(0)" ::: "memory");
  }
#undef DMA
}

// -------------------------------------------------------------------------
extern "C" void kernel_launch(void* const* d_in, const int* in_sizes, int n_in,
                              void* d_out, int out_size, void* d_ws, size_t ws_size,
                              hipStream_t stream)
{
  (void)in_sizes; (void)n_in; (void)out_size; (void)d_ws; (void)ws_size;
  const float* x   = (const float*)d_in[0];
  const float* enc = (const float*)d_in[1];
  const float* msk = (const float*)d_in[2];
  const float* w1  = (const float*)d_in[3];
  const float* b1  = (const float*)d_in[4];
  const float* w2  = (const float*)d_in[5];
  const float* b2  = (const float*)d_in[6];
  const float* w3  = (const float*)d_in[7];
  const float* b3  = (const float*)d_in[8];

  float* out = (float*)d_out;
  float* mu  = out;                       // [B,T,S]  (row 0 carries stats pre-dp)
  float* pi  = out + NMU;                 // [B,T,S,2] (tail quarters carry wdp_f16 pre-dp)
  float* al  = out + NMU + NPI;           // [B,T,S]
  float* wsp = out + NMU + NPI + NMU;     // [B,T,H] fp32

  // conv/einsum scratch inside pi region (all consumed before norm runs)
  _Float16*  h1  = (_Float16*)(pi + 26000000);       // 16.384M halves
  _Float16*  h2  = (_Float16*)(pi + 35000000);       // 16.384M halves
  _Float16*  wc1 = (_Float16*)(pi + 44000000);
  _Float16*  wc2 = (_Float16*)(pi + 44100000);
  _Float16*  wc3 = (_Float16*)(pi + 44300000);
  _Float16*  encf = (_Float16*)(pi + 44600000);      // 3.28M halves
  float*     pm   = pi + 46300000;                   // [B][32][S] partial M
  float*     pl   = pi + 47200000;                   // [B][32][S] partial L

  hipLaunchKernelGGL(wprep, dim3((256*5*96 +255)/256), dim3(256), 0, stream, w1, wc1, C0_, 96);
  hipLaunchKernelGGL(wprep, dim3((256*5*256+255)/256), dim3(256), 0, stream, w2, wc2, H_, 256);
  hipLaunchKernelGGL(wprep, dim3((256*5*256+255)/256), dim3(256), 0, stream, w3, wc3, H_, 256);
  hipLaunchKernelGGL(ecast, dim3(B_*S_*H_/4/256), dim3(256), 0, stream, enc, encf);

  dim3 cgrid((T_ + 63) / 64, B_);
  hipLaunchKernelGGL((conv_mfma<C0_,  96, true,  false>), cgrid, dim3(256), 0, stream,
                     (const void*)x,  wc1, b1, (void*)h1);
  hipLaunchKernelGGL((conv_mfma<H_,  256, false, false>), cgrid, dim3(256), 0, stream,
                     (const void*)h1, wc2, b2, (void*)h2);
  hipLaunchKernelGGL((conv_mfma<H_,  256, false, true >), cgrid, dim3(256), 0, stream,
                     (const void*)h2, wc3, b3, (void*)wsp);

  hipLaunchKernelGGL(einsum_mfma, dim3((T_ + 63) / 64, (S_ + 255) / 256, B_), dim3(256),
                     0, stream, wsp, encf, al, pm, pl);
  hipLaunchKernelGGL(stats_reduce, dim3((B_ * S_ + 255) / 256), dim3(256), 0, stream,
                     pm, pl, mu);
  hipLaunchKernelGGL(norm_kernel, dim3(NMU / 4 / 256), dim3(256), 0, stream, al, msk, mu, pi);
  hipLaunchKernelGGL(dp_skew4, dim3(B_), dim3(256), 0, stream, mu, pi);
}

// Round 22
// 925.781 us; speedup vs baseline: 1.0165x; 1.0165x over previous
//
#include <hip/hip_runtime.h>
#include <hip/hip_bf16.h>

#define B_ 32
#define T_ 2000
#define S_ 400
#define C0_ 80
#define H_ 256

static constexpr float NEGV = -1e9f;
static constexpr int NMU  = B_ * T_ * S_;       // 25,600,000
static constexpr int NPI  = 2 * NMU;            // 51,200,000

typedef _Float16 f16x8 __attribute__((ext_vector_type(8)));
typedef float    f32x4 __attribute__((ext_vector_type(4)));

// ---------------- weight repack: wcat[co][k*CPAD+ci] = w[k][ci][co] ------
__global__ __launch_bounds__(256)
void wprep(const float* __restrict__ w, _Float16* __restrict__ wcat,
           int CIN, int CPAD)
{
  const int tot = 256 * 5 * CPAD;
  int idx = blockIdx.x * 256 + threadIdx.x;
  if (idx >= tot) return;
  int co  = idx / (5 * CPAD);
  int rem = idx - co * (5 * CPAD);
  int k   = rem / CPAD;
  int ci  = rem - k * CPAD;
  float v = (ci < CIN) ? w[((size_t)k * CIN + ci) * H_ + co] : 0.f;
  wcat[idx] = (_Float16)v;
}

// ---------------- cast src_enc to f16 ------------------------------------
__global__ __launch_bounds__(256)
void ecast(const float* __restrict__ e, _Float16* __restrict__ ef)
{
  const int n4 = B_ * S_ * H_ / 4;
  int idx = blockIdx.x * 256 + threadIdx.x;
  if (idx >= n4) return;
  float4 v = ((const float4*)e)[idx];
  _Float16* d = ef + (size_t)idx * 4;
  d[0] = (_Float16)v.x; d[1] = (_Float16)v.y;
  d[2] = (_Float16)v.z; d[3] = (_Float16)v.w;
}

// ---------------- conv1d (K=5, SAME) + bias + tanh via f16 MFMA ----------
template<int CIN, int CPAD, bool INF32, bool OUTF32>
__global__ __launch_bounds__(256)
void conv_mfma(const void* __restrict__ xin, const _Float16* __restrict__ wcat,
               const float* __restrict__ bias, void* __restrict__ yout)
{
  constexpr int KK  = 5 * CPAD;      // 480 / 1280
  constexpr int NS  = KK / 32;       // 15 / 40
  constexpr int STR = CPAD + 8;      // LDS row stride
  __shared__ _Float16 xs[68 * STR];
  const int b   = blockIdx.y;
  const int t0  = blockIdx.x * 64;
  const int tid = threadIdx.x;
  const int w   = tid >> 6;
  const int l   = tid & 63;

  if constexpr (INF32) {
    const float* xb = (const float*)xin + (size_t)b * T_ * CIN;
    constexpr int NG = CPAD / 4;
    for (int idx = tid; idx < 68 * NG; idx += 256) {
      int j = idx / NG, g = idx - j * NG;
      int t = t0 - 2 + j;
      int c = g * 4;
      float4 v = make_float4(0.f, 0.f, 0.f, 0.f);
      if (t >= 0 && t < T_ && c < CIN) v = *(const float4*)&xb[(size_t)t * CIN + c];
      _Float16* d = &xs[j * STR + c];
      d[0] = (_Float16)v.x; d[1] = (_Float16)v.y;
      d[2] = (_Float16)v.z; d[3] = (_Float16)v.w;
    }
  } else {
    const _Float16* xb = (const _Float16*)xin + (size_t)b * T_ * CIN;
    constexpr int NG = CPAD / 8;
    for (int idx = tid; idx < 68 * NG; idx += 256) {
      int j = idx / NG, g = idx - j * NG;
      int t = t0 - 2 + j;
      f16x8 v = {(_Float16)0,(_Float16)0,(_Float16)0,(_Float16)0,
                 (_Float16)0,(_Float16)0,(_Float16)0,(_Float16)0};
      if (t >= 0 && t < T_) v = *(const f16x8*)&xb[(size_t)t * CIN + g * 8];
      *(f16x8*)&xs[j * STR + g * 8] = v;
    }
  }
  __syncthreads();

  const int lr = l & 15;
  const int lk = (l >> 4) * 8;

  f32x4 acc[4][4];
  const f32x4 zz = {0.f, 0.f, 0.f, 0.f};
#pragma unroll
  for (int i = 0; i < 4; i++)
#pragma unroll
    for (int j = 0; j < 4; j++) acc[i][j] = zz;

  const _Float16* wbase = wcat + (size_t)(w * 64 + lr) * KK + lk;

  for (int kk = 0; kk < NS; kk++) {
    const int p  = kk * 32;
    const int k  = p / CPAD;
    const int ci = p - k * CPAD;
    f16x8 a0 = *(const f16x8*)&xs[( 0 + lr + k) * STR + ci + lk];
    f16x8 a1 = *(const f16x8*)&xs[(16 + lr + k) * STR + ci + lk];
    f16x8 a2 = *(const f16x8*)&xs[(32 + lr + k) * STR + ci + lk];
    f16x8 a3 = *(const f16x8*)&xs[(48 + lr + k) * STR + ci + lk];
    f16x8 w0 = *(const f16x8*)&wbase[(size_t)( 0) * KK + p];
    f16x8 w1 = *(const f16x8*)&wbase[(size_t)(16) * KK + p];
    f16x8 w2 = *(const f16x8*)&wbase[(size_t)(32) * KK + p];
    f16x8 w3 = *(const f16x8*)&wbase[(size_t)(48) * KK + p];
    acc[0][0] = __builtin_amdgcn_mfma_f32_16x16x32_f16(a0, w0, acc[0][0], 0, 0, 0);
    acc[0][1] = __builtin_amdgcn_mfma_f32_16x16x32_f16(a0, w1, acc[0][1], 0, 0, 0);
    acc[0][2] = __builtin_amdgcn_mfma_f32_16x16x32_f16(a0, w2, acc[0][2], 0, 0, 0);
    acc[0][3] = __builtin_amdgcn_mfma_f32_16x16x32_f16(a0, w3, acc[0][3], 0, 0, 0);
    acc[1][0] = __builtin_amdgcn_mfma_f32_16x16x32_f16(a1, w0, acc[1][0], 0, 0, 0);
    acc[1][1] = __builtin_amdgcn_mfma_f32_16x16x32_f16(a1, w1, acc[1][1], 0, 0, 0);
    acc[1][2] = __builtin_amdgcn_mfma_f32_16x16x32_f16(a1, w2, acc[1][2], 0, 0, 0);
    acc[1][3] = __builtin_amdgcn_mfma_f32_16x16x32_f16(a1, w3, acc[1][3], 0, 0, 0);
    acc[2][0] = __builtin_amdgcn_mfma_f32_16x16x32_f16(a2, w0, acc[2][0], 0, 0, 0);
    acc[2][1] = __builtin_amdgcn_mfma_f32_16x16x32_f16(a2, w1, acc[2][1], 0, 0, 0);
    acc[2][2] = __builtin_amdgcn_mfma_f32_16x16x32_f16(a2, w2, acc[2][2], 0, 0, 0);
    acc[2][3] = __builtin_amdgcn_mfma_f32_16x16x32_f16(a2, w3, acc[2][3], 0, 0, 0);
    acc[3][0] = __builtin_amdgcn_mfma_f32_16x16x32_f16(a3, w0, acc[3][0], 0, 0, 0);
    acc[3][1] = __builtin_amdgcn_mfma_f32_16x16x32_f16(a3, w1, acc[3][1], 0, 0, 0);
    acc[3][2] = __builtin_amdgcn_mfma_f32_16x16x32_f16(a3, w2, acc[3][2], 0, 0, 0);
    acc[3][3] = __builtin_amdgcn_mfma_f32_16x16x32_f16(a3, w3, acc[3][3], 0, 0, 0);
  }

#pragma unroll
  for (int ct = 0; ct < 4; ct++) {
    const int co = w * 64 + ct * 16 + lr;
    const float bv = bias[co];
#pragma unroll
    for (int tt = 0; tt < 4; tt++) {
#pragma unroll
      for (int r = 0; r < 4; r++) {
        const int t = t0 + tt * 16 + (l >> 4) * 4 + r;
        if (t < T_) {
          float v = tanhf(acc[tt][ct][r] + bv);
          if constexpr (OUTF32)
            ((float*)yout)[((size_t)b * T_ + t) * H_ + co] = v;
          else
            ((_Float16*)yout)[((size_t)b * T_ + t) * H_ + co] = (_Float16)v;
        }
      }
    }
  }
}

// ---------------- einsum via f16 MFMA + fused column-stats partials ------
__global__ __launch_bounds__(256)
void einsum_mfma(const float* __restrict__ A, const _Float16* __restrict__ E,
                 float* __restrict__ Wg,
                 float* __restrict__ pm, float* __restrict__ pl)
{
  constexpr int STR = H_ + 8;        // 264
  __shared__ _Float16 xs[64 * STR];  // 33.8 KB
  const int b   = blockIdx.z;
  const int t0  = blockIdx.x * 64;
  const int s0  = blockIdx.y * 256;
  const int tid = threadIdx.x;
  const int w   = tid >> 6;
  const int l   = tid & 63;

  const float* Ab = A + (size_t)b * T_ * H_;
  for (int idx = tid; idx < 64 * 64; idx += 256) {
    int row = idx >> 6, g = idx & 63;
    int t = t0 + row;
    float4 v = make_float4(0.f, 0.f, 0.f, 0.f);
    if (t < T_) v = *(const float4*)&Ab[(size_t)t * H_ + 4 * g];
    _Float16* d = &xs[row * STR + 4 * g];
    d[0] = (_Float16)v.x; d[1] = (_Float16)v.y;
    d[2] = (_Float16)v.z; d[3] = (_Float16)v.w;
  }
  __syncthreads();

  const int lr = l & 15;
  const int lk = (l >> 4) * 8;

  f32x4 acc[4][4];
  const f32x4 zz = {0.f, 0.f, 0.f, 0.f};
#pragma unroll
  for (int i = 0; i < 4; i++)
#pragma unroll
    for (int j = 0; j < 4; j++) acc[i][j] = zz;

  const _Float16* Eb = E + (size_t)b * S_ * H_;
  const int sr = s0 + w * 64 + lr;
  const _Float16* e0 = Eb + (size_t)((sr      < S_) ? sr      : (S_ - 1)) * H_ + lk;
  const _Float16* e1 = Eb + (size_t)((sr + 16 < S_) ? sr + 16 : (S_ - 1)) * H_ + lk;
  const _Float16* e2 = Eb + (size_t)((sr + 32 < S_) ? sr + 32 : (S_ - 1)) * H_ + lk;
  const _Float16* e3 = Eb + (size_t)((sr + 48 < S_) ? sr + 48 : (S_ - 1)) * H_ + lk;

#pragma unroll
  for (int kk = 0; kk < 8; kk++) {
    const int p = kk * 32;
    f16x8 a0 = *(const f16x8*)&xs[( 0 + lr) * STR + p + lk];
    f16x8 a1 = *(const f16x8*)&xs[(16 + lr) * STR + p + lk];
    f16x8 a2 = *(const f16x8*)&xs[(32 + lr) * STR + p + lk];
    f16x8 a3 = *(const f16x8*)&xs[(48 + lr) * STR + p + lk];
    f16x8 w0 = *(const f16x8*)&e0[p];
    f16x8 w1 = *(const f16x8*)&e1[p];
    f16x8 w2 = *(const f16x8*)&e2[p];
    f16x8 w3 = *(const f16x8*)&e3[p];
    acc[0][0] = __builtin_amdgcn_mfma_f32_16x16x32_f16(a0, w0, acc[0][0], 0, 0, 0);
    acc[0][1] = __builtin_amdgcn_mfma_f32_16x16x32_f16(a0, w1, acc[0][1], 0, 0, 0);
    acc[0][2] = __builtin_amdgcn_mfma_f32_16x16x32_f16(a0, w2, acc[0][2], 0, 0, 0);
    acc[0][3] = __builtin_amdgcn_mfma_f32_16x16x32_f16(a0, w3, acc[0][3], 0, 0, 0);
    acc[1][0] = __builtin_amdgcn_mfma_f32_16x16x32_f16(a1, w0, acc[1][0], 0, 0, 0);
    acc[1][1] = __builtin_amdgcn_mfma_f32_16x16x32_f16(a1, w1, acc[1][1], 0, 0, 0);
    acc[1][2] = __builtin_amdgcn_mfma_f32_16x16x32_f16(a1, w2, acc[1][2], 0, 0, 0);
    acc[1][3] = __builtin_amdgcn_mfma_f32_16x16x32_f16(a1, w3, acc[1][3], 0, 0, 0);
    acc[2][0] = __builtin_amdgcn_mfma_f32_16x16x32_f16(a2, w0, acc[2][0], 0, 0, 0);
    acc[2][1] = __builtin_amdgcn_mfma_f32_16x16x32_f16(a2, w1, acc[2][1], 0, 0, 0);
    acc[2][2] = __builtin_amdgcn_mfma_f32_16x16x32_f16(a2, w2, acc[2][2], 0, 0, 0);
    acc[2][3] = __builtin_amdgcn_mfma_f32_16x16x32_f16(a2, w3, acc[2][3], 0, 0, 0);
    acc[3][0] = __builtin_amdgcn_mfma_f32_16x16x32_f16(a3, w0, acc[3][0], 0, 0, 0);
    acc[3][1] = __builtin_amdgcn_mfma_f32_16x16x32_f16(a3, w1, acc[3][1], 0, 0, 0);
    acc[3][2] = __builtin_amdgcn_mfma_f32_16x16x32_f16(a3, w2, acc[3][2], 0, 0, 0);
    acc[3][3] = __builtin_amdgcn_mfma_f32_16x16x32_f16(a3, w3, acc[3][3], 0, 0, 0);
  }

  float* Wb = Wg + (size_t)b * T_ * S_;
#pragma unroll
  for (int ct = 0; ct < 4; ct++) {
    const int s = s0 + w * 64 + ct * 16 + lr;
    if (s < S_) {
#pragma unroll
      for (int tt = 0; tt < 4; tt++) {
#pragma unroll
        for (int r = 0; r < 4; r++) {
          const int t = t0 + tt * 16 + (l >> 4) * 4 + r;
          if (t < T_) Wb[(size_t)t * S_ + s] = acc[tt][ct][r];
        }
      }
    }
  }

  // ---- fused per-(t-block, s) column stats ----
  const int tblk = blockIdx.x;
#pragma unroll
  for (int ct = 0; ct < 4; ct++) {
    float M = -3e38f;
#pragma unroll
    for (int tt = 0; tt < 4; tt++)
#pragma unroll
      for (int r = 0; r < 4; r++) {
        const int t = t0 + tt * 16 + (l >> 4) * 4 + r;
        if (t < T_) M = fmaxf(M, acc[tt][ct][r]);
      }
    float L = 0.f;
#pragma unroll
    for (int tt = 0; tt < 4; tt++)
#pragma unroll
      for (int r = 0; r < 4; r++) {
        const int t = t0 + tt * 16 + (l >> 4) * 4 + r;
        if (t < T_) L += __expf(acc[tt][ct][r] - M);
      }
#pragma unroll
    for (int mk = 16; mk <= 32; mk <<= 1) {
      float Mo = __shfl_xor(M, mk);
      float Lo = __shfl_xor(L, mk);
      float Mn = fmaxf(M, Mo);
      L = L * __expf(M - Mn) + Lo * __expf(Mo - Mn);
      M = Mn;
    }
    if ((l >> 4) == 0) {
      const int s = s0 + w * 64 + ct * 16 + lr;
      if (s < S_) {
        pm[((size_t)b * 32 + tblk) * S_ + s] = M;
        pl[((size_t)b * 32 + tblk) * S_ + s] = L;
      }
    }
  }
}

// ---------------- reduce 32 t-block partials -> stats[b][s] = M + lnL ----
__global__ __launch_bounds__(256)
void stats_reduce(const float* __restrict__ pm, const float* __restrict__ pl,
                  float* __restrict__ statsOut)
{
  int idx = blockIdx.x * 256 + threadIdx.x;
  if (idx >= B_ * S_) return;
  int b = idx / S_, s = idx - b * S_;
  float M = -3e38f, L = 0.f;
#pragma unroll 4
  for (int k = 0; k < 32; k++) {
    float m = pm[((size_t)b * 32 + k) * S_ + s];
    float l = pl[((size_t)b * 32 + k) * S_ + s];
    float Mn = fmaxf(M, m);
    L = L * __expf(M - Mn) + l * __expf(m - Mn);
    M = Mn;
  }
  statsOut[(size_t)b * S_ + s] = M + __logf(L);
}

// ---------------- normalize: al = exp(raw-stat); wdp = al*mask*log2e ----
__global__ __launch_bounds__(256)
void norm_kernel(float* __restrict__ al, const float* __restrict__ Mk,
                 const float* __restrict__ stats, float* __restrict__ wdp)
{
  constexpr float C2 = 1.44269504f;
  const int gid = blockIdx.x * 256 + threadIdx.x;
  if (gid >= NMU / 4) return;
  const int b   = gid / (T_ * S_ / 4);
  const int rem = gid - b * (T_ * S_ / 4);
  const int s4  = rem % (S_ / 4);
  const float4 st4 = *(const float4*)&stats[(size_t)b * S_ + 4 * s4];
  float4 r = ((const float4*)al)[gid];
  float4 k = ((const float4*)Mk)[gid];
  float4 a;
  a.x = __expf(r.x - st4.x);
  a.y = __expf(r.y - st4.y);
  a.z = __expf(r.z - st4.z);
  a.w = __expf(r.w - st4.w);
  ((float4*)al)[gid] = a;
  ((float4*)wdp)[gid] = make_float4(a.x * k.x * C2, a.y * k.y * C2,
                                    a.z * k.z * C2, a.w * k.w * C2);
}

// ---------------- DP: skewed 4-wave pipeline, 16 rows/phase --------------
// Wave w owns cols [100w,100w+100) (2 cells/lane) and runs block j
// (rows 16j+1..16j+16) at phase p=j+w+1 (base case row 0 at p=w).
// 129 phases. Ring 96 rows (153.6 KB, mod-96 running-counter slots).
// vmcnt(40) once per phase at PHASE START retires everything >= 2 phases
// old (incl. the 2-phase-lead DMAs), never waits on current stores.
// Base-2 space throughout.
__global__ __launch_bounds__(256, 1)
void dp_skew3(const float* Wdp, float* muOut, float* piOut)
{
  __shared__ float ring[96 * S_];     // 153.6 KB
  __shared__ float bnd[64][4];
  const int b = blockIdx.x;
  const int w = threadIdx.x >> 6;
  const int l = threadIdx.x & 63;
  const int lc = (l < 50) ? l : 49;
  const bool act = (l < 50);
  const int sc = 100 * w + 2 * lc;

  const float* wb  = Wdp   + (size_t)b * T_ * S_;
  float*       mub = muOut + (size_t)b * T_ * S_;
  float*       pib = piOut + (size_t)(2 * b) * T_ * S_;

  constexpr float LN2  = 0.693147181f;
  constexpr float NEGN = -1.44269504e9f;   // -1e9 * log2(e)

#define DMA(row, slot)                                                      \
  { const char* s_ = (const char*)(wb + (size_t)(row) * S_);                \
    char* d_ = (char*)ring + ((slot) * 1600);                               \
    __builtin_amdgcn_global_load_lds(                                       \
      (const __attribute__((address_space(1))) void*)(s_ + l * 16),         \
      (__attribute__((address_space(3))) void*)(d_ + l * 16), 16, 0, 0);    \
    if (l < 36)                                                             \
      __builtin_amdgcn_global_load_lds(                                     \
        (const __attribute__((address_space(1))) void*)(s_ + 1024 + l*16),  \
        (__attribute__((address_space(3))) void*)(d_ + 1024 + l*16), 16, 0, 0); }

  // prologue: rows 0..16 (wave w: rows 4w..4w+3; wave 0 also row 16)
#pragma unroll
  for (int i = 0; i < 4; ++i) { const int r0 = 4 * w + i; DMA(r0, r0) }
  if (w == 0) DMA(16, 16)
  asm volatile("s_waitcnt vmcnt(0)" ::: "memory");
  __syncthreads();

  float n0 = NEGN, n1 = NEGN;
  int rs = 1;             // ring slot of row 16j+1 for this wave's next block
  int ds = 17 + 4 * w;    // ring slot of first DMA row at phase 0

  for (int p = 0; p <= 128; ++p) {
    __builtin_amdgcn_s_barrier();
    asm volatile("s_waitcnt vmcnt(40)" ::: "memory");
    const int j = p - w - 1;

    // ---- DMA block p+1: rows 16(p+1)+1+4w .. +3 ----
    {
      const int dr = 16 * (p + 1) + 1 + 4 * w;
#pragma unroll
      for (int q = 0; q < 4; ++q) {
        if (dr + q < T_) {
          int s2 = ds + q; if (s2 >= 96) s2 -= 96;
          DMA(dr + q, s2)
        }
      }
      ds += 16; if (ds >= 96) ds -= 96;
    }

    if (p == w) {
      // base case: row 0 (slot 0, prologue-staged)
      float2 c0v = *(const float2*)&ring[sc];
      n0 = c0v.x + ((sc == 0) ? 0.f : NEGN);
      n1 = c0v.y + NEGN;
      if (act) {
        *(float2*)&mub[sc] = make_float2(n0 * LN2, n1 * LN2);
        *(float4*)&pib[2 * sc] = make_float4(1.f, 0.f, 1.f, 0.f);
      }
      if (l == 49) bnd[0][w] = n1;
    } else if (j >= 0 && j <= 124) {
      const int tb = 16 * j + 1;
      // ---- hoisted independent reads ----
      float2 cur[16];
      float  bq[16];
#pragma unroll
      for (int k = 0; k < 16; ++k) {
        const int t = tb + k;
        int sk = rs + k; if (sk >= 96) sk -= 96;
        cur[k] = (t < T_) ? *(const float2*)&ring[sk * S_ + sc]
                          : make_float2(0.f, 0.f);
        bq[k] = (w > 0) ? bnd[(t - 1) & 63][w - 1] : NEGN;
      }
      // ---- compute 16 steps ----
      float* mrow = mub + (size_t)tb * S_ + sc;
      float* prow = pib + (size_t)tb * (2 * S_) + 2 * sc;
#pragma unroll
      for (int k = 0; k < 16; ++k) {
        const int t = tb + k;
        if (t < T_) {                                    // wave-uniform
          float sh = __shfl_up(n1, 1);
          float sft0 = (l == 0) ? bq[k] : sh;
          float d0 = n0 - sft0;
          float e0; asm("v_exp_f32 %0, %1" : "=v"(e0) : "v"(-fabsf(d0)));
          float q0 = 1.f + e0;
          float lg0; asm("v_log_f32 %0, %1" : "=v"(lg0) : "v"(q0));
          float rc0; asm("v_rcp_f32 %0, %1" : "=v"(rc0) : "v"(q0));
          float p00 = (d0 >= 0.f) ? rc0 : 1.f - rc0;
          float nn0 = cur[k].x + fmaxf(n0, sft0) + lg0;
          float d1 = n1 - n0;
          float e1; asm("v_exp_f32 %0, %1" : "=v"(e1) : "v"(-fabsf(d1)));
          float q1 = 1.f + e1;
          float lg1; asm("v_log_f32 %0, %1" : "=v"(lg1) : "v"(q1));
          float rc1; asm("v_rcp_f32 %0, %1" : "=v"(rc1) : "v"(q1));
          float p01 = (d1 >= 0.f) ? rc1 : 1.f - rc1;
          float nn1 = cur[k].y + fmaxf(n1, n0) + lg1;
          if (act) {
            *(float2*)mrow = make_float2(nn0 * LN2, nn1 * LN2);
            *(float4*)prow = make_float4(p00, 1.f - p00, p01, 1.f - p01);
          }
          n0 = nn0; n1 = nn1;
          if (l == 49) bnd[t & 63][w] = n1;
        }
        mrow += S_;
        prow += 2 * S_;
      }
      rs += 16; if (rs >= 96) rs -= 96;
    }
    // publish bnd before the next barrier
    asm volatile("s_waitcnt lgkmcnt(0)" ::: "memory");
  }
#undef DMA
}

// -------------------------------------------------------------------------
extern "C" void kernel_launch(void* const* d_in, const int* in_sizes, int n_in,
                              void* d_out, int out_size, void* d_ws, size_t ws_size,
                              hipStream_t stream)
{
  (void)in_sizes; (void)n_in; (void)out_size; (void)d_ws; (void)ws_size;
  const float* x   = (const float*)d_in[0];
  const float* enc = (const float*)d_in[1];
  const float* msk = (const float*)d_in[2];
  const float* w1  = (const float*)d_in[3];
  const float* b1  = (const float*)d_in[4];
  const float* w2  = (const float*)d_in[5];
  const float* b2  = (const float*)d_in[6];
  const float* w3  = (const float*)d_in[7];
  const float* b3  = (const float*)d_in[8];

  float* out = (float*)d_out;
  float* mu  = out;                       // [B,T,S]  (holds wdp before dp)
  float* pi  = out + NMU;                 // [B,T,S,2]
  float* al  = out + NMU + NPI;           // [B,T,S]
  float* wsp = out + NMU + NPI + NMU;     // [B,T,H] fp32

  // scratch inside pi region (consumed before dp_skew3 writes pi)
  _Float16*  h1  = (_Float16*)(pi + 26000000);       // 16.384M halves
  _Float16*  h2  = (_Float16*)(pi + 35000000);       // 16.384M halves
  _Float16*  wc1 = (_Float16*)(pi + 44000000);
  _Float16*  wc2 = (_Float16*)(pi + 44100000);
  _Float16*  wc3 = (_Float16*)(pi + 44300000);
  _Float16*  encf = (_Float16*)(pi + 44600000);      // 3.28M halves
  float*     pm   = pi + 46300000;                   // [B][32][S] partial M
  float*     pl   = pi + 47200000;                   // [B][32][S] partial L
  float*     pistats = pi + NPI - 13056;             // [B,S] softmax stats

  hipLaunchKernelGGL(wprep, dim3((256*5*96 +255)/256), dim3(256), 0, stream, w1, wc1, C0_, 96);
  hipLaunchKernelGGL(wprep, dim3((256*5*256+255)/256), dim3(256), 0, stream, w2, wc2, H_, 256);
  hipLaunchKernelGGL(wprep, dim3((256*5*256+255)/256), dim3(256), 0, stream, w3, wc3, H_, 256);
  hipLaunchKernelGGL(ecast, dim3(B_*S_*H_/4/256), dim3(256), 0, stream, enc, encf);

  dim3 cgrid((T_ + 63) / 64, B_);
  hipLaunchKernelGGL((conv_mfma<C0_,  96, true,  false>), cgrid, dim3(256), 0, stream,
                     (const void*)x,  wc1, b1, (void*)h1);
  hipLaunchKernelGGL((conv_mfma<H_,  256, false, false>), cgrid, dim3(256), 0, stream,
                     (const void*)h1, wc2, b2, (void*)h2);
  hipLaunchKernelGGL((conv_mfma<H_,  256, false, true >), cgrid, dim3(256), 0, stream,
                     (const void*)h2, wc3, b3, (void*)wsp);

  hipLaunchKernelGGL(einsum_mfma, dim3((T_ + 63) / 64, (S_ + 255) / 256, B_), dim3(256),
                     0, stream, wsp, encf, al, pm, pl);
  hipLaunchKernelGGL(stats_reduce, dim3((B_ * S_ + 255) / 256), dim3(256), 0, stream,
                     pm, pl, pistats);
  hipLaunchKernelGGL(norm_kernel, dim3(NMU / 4 / 256), dim3(256), 0, stream, al, msk, pistats, mu);
  hipLaunchKernelGGL(dp_skew3, dim3(B_), dim3(256), 0, stream, mu, mu, pi);
}